// Round 8
// baseline (334.369 us; speedup 1.0000x reference)
//
#include <hip/hip_runtime.h>

#define NEG 0.2f

// Zero-fill for count (hipMemsetAsync small-fill path is pathological ~1GB/s).
__global__ __launch_bounds__(256) void k_zero(int* __restrict__ p, int n) {
    int i = blockIdx.x * 256 + threadIdx.x;
    if (i < n) p[i] = 0;
}

// h = relu(x) @ W, register-blocked 4x4 (R7 version, kept).
__global__ __launch_bounds__(128) void k_node(
    const float* __restrict__ x, const float* __restrict__ W,
    const float* __restrict__ att_src, const float* __restrict__ att_dst,
    float* __restrict__ hbuf, float* __restrict__ a_src, float* __restrict__ a_dst, int N) {
    __shared__ float xs[128 * 36];
    __shared__ float Wl[128 * 64];
    const int t  = threadIdx.x;
    const int tn = t & 7;
    const int tc = t >> 3;
    const int node0 = blockIdx.x * 32;

    for (int j = t; j < 128 * 64; j += 128) Wl[j] = W[j];
    for (int j = t; j < 32 * 128; j += 128) {
        int n = j >> 7, k = j & 127;
        int nn = node0 + n;
        xs[k * 36 + n] = (nn < N) ? fmaxf(x[(size_t)nn * 128 + k], 0.f) : 0.f;
    }
    __syncthreads();

    float4 acc[4] = {{0,0,0,0},{0,0,0,0},{0,0,0,0},{0,0,0,0}};
#pragma unroll 8
    for (int k = 0; k < 128; ++k) {
        const float4 xv = *(const float4*)(xs + k * 36 + 4 * tn);
        const float4 wv = *(const float4*)(Wl + k * 64 + 4 * tc);
        acc[0].x = fmaf(xv.x, wv.x, acc[0].x); acc[0].y = fmaf(xv.x, wv.y, acc[0].y);
        acc[0].z = fmaf(xv.x, wv.z, acc[0].z); acc[0].w = fmaf(xv.x, wv.w, acc[0].w);
        acc[1].x = fmaf(xv.y, wv.x, acc[1].x); acc[1].y = fmaf(xv.y, wv.y, acc[1].y);
        acc[1].z = fmaf(xv.y, wv.z, acc[1].z); acc[1].w = fmaf(xv.y, wv.w, acc[1].w);
        acc[2].x = fmaf(xv.z, wv.x, acc[2].x); acc[2].y = fmaf(xv.z, wv.y, acc[2].y);
        acc[2].z = fmaf(xv.z, wv.z, acc[2].z); acc[2].w = fmaf(xv.z, wv.w, acc[2].w);
        acc[3].x = fmaf(xv.w, wv.x, acc[3].x); acc[3].y = fmaf(xv.w, wv.y, acc[3].y);
        acc[3].z = fmaf(xv.w, wv.z, acc[3].z); acc[3].w = fmaf(xv.w, wv.w, acc[3].w);
    }

#pragma unroll
    for (int n = 0; n < 4; ++n) {
        int nn = node0 + 4 * tn + n;
        if (nn < N) *(float4*)(hbuf + (size_t)nn * 64 + 4 * tc) = acc[n];
    }

    const float4 as4 = *(const float4*)(att_src + 4 * tc);
    const float4 ad4 = *(const float4*)(att_dst + 4 * tc);
    int head = (t >= 64) ? 1 : 0;
#pragma unroll
    for (int n = 0; n < 4; ++n) {
        float vs = acc[n].x * as4.x + acc[n].y * as4.y + acc[n].z * as4.z + acc[n].w * as4.w;
        float vd = acc[n].x * ad4.x + acc[n].y * ad4.y + acc[n].z * ad4.z + acc[n].w * ad4.w;
#pragma unroll
        for (int m = 8; m <= 32; m <<= 1) {
            vs += __shfl_xor(vs, m, 64);
            vd += __shfl_xor(vd, m, 64);
        }
        int nn = node0 + 4 * tn + n;
        if ((t & 63) < 8 && nn < N) {
            a_src[nn * 2 + head] = vs;
            a_dst[nn * 2 + head] = vd;
        }
    }
}

// In-degree histogram (1 int atomic/edge) + wke fold (block 0).
__global__ __launch_bounds__(256) void k_hist(
    const int* __restrict__ dstI, int* __restrict__ count, long long E,
    const float* __restrict__ W_edge, const float* __restrict__ att_edge,
    float* __restrict__ wke) {
    if (blockIdx.x == 0 && threadIdx.x < 128) {
        int hh = threadIdx.x >> 6;
        int k  = threadIdx.x & 63;
        float s = 0.f;
#pragma unroll
        for (int c = 0; c < 32; ++c)
            s += W_edge[k * 64 + hh * 32 + c] * att_edge[hh * 32 + c];
        wke[hh * 64 + k] = s;
    }
    long long i0 = (long long)blockIdx.x * 256 + threadIdx.x;
    long long stride = (long long)gridDim.x * 256;
    for (long long i = i0; i < E; i += stride)
        atomicAdd(&count[dstI[i]], 1);
}

// Exclusive scan, 1024 elements per block (256 thr x 4).
__global__ __launch_bounds__(256) void k_scan1(const int* __restrict__ cnt, int* __restrict__ offs,
                                               int* __restrict__ bsum, int N) {
    __shared__ int ts[256];
    int t = threadIdx.x, blk = blockIdx.x;
    int base = blk * 1024 + t * 4;
    int v[4], s = 0;
#pragma unroll
    for (int i = 0; i < 4; ++i) {
        int idx = base + i;
        v[i] = (idx < N) ? cnt[idx] : 0;
        s += v[i];
    }
    ts[t] = s;
    __syncthreads();
    for (int off = 1; off < 256; off <<= 1) {
        int y = (t >= off) ? ts[t - off] : 0;
        __syncthreads();
        ts[t] += y;
        __syncthreads();
    }
    int run = ts[t] - s;
#pragma unroll
    for (int i = 0; i < 4; ++i) {
        int idx = base + i;
        if (idx < N) offs[idx] = run;
        run += v[i];
    }
    if (t == 255) bsum[blk] = ts[255];
}

// Single-wave shuffle scan over block sums (nb <= 64).
__global__ void k_scan2(int* __restrict__ bsum, int nb) {
    int t = threadIdx.x;
    int orig = (t < nb) ? bsum[t] : 0;
    int v = orig;
#pragma unroll
    for (int off = 1; off < 64; off <<= 1) {
        int y = __shfl_up(v, off, 64);
        if (t >= off) v += y;
    }
    if (t < nb) bsum[t] = v - orig;
}

__global__ void k_scan3(int* __restrict__ offs, const int* __restrict__ bsum,
                        int* __restrict__ cursor, int N) {
    int idx = blockIdx.x * 256 + threadIdx.x;
    if (idx < N) {
        int o = offs[idx] + bsum[idx >> 10];
        offs[idx] = o;
        cursor[idx] = o;
    }
}

// CSR scatter of (eid, src) pairs only — 8B per edge. No edge_attr touch.
__global__ __launch_bounds__(256) void k_sort(
    const int* __restrict__ srcI, const int* __restrict__ dstI,
    int* __restrict__ cursor, int2* __restrict__ epos, long long E) {
    long long i0 = (long long)blockIdx.x * 256 + threadIdx.x;
    long long stride = (long long)gridDim.x * 256;
    for (long long e = i0; e < E; e += stride) {
        int s = srcI[e], d = dstI[e];
        int pos = atomicAdd(&cursor[d], 1);
        epos[pos] = make_int2((int)e, s);
    }
}

// Per-node aggregation with fused a_edge dot: 64 lanes/node, 4-way edge-parallel.
// Per edge: 16 sub-lanes gather the full 256B edge_attr row + hbuf row,
// dot vs LDS wke, butterfly-reduce over lane bits 0..3.
__global__ __launch_bounds__(256) void k_agg(
    const int2* __restrict__ epos, const int* __restrict__ offs,
    const int* __restrict__ count, const float* __restrict__ edge_attr,
    const float* __restrict__ wke, const float* __restrict__ a_src,
    const float* __restrict__ a_dst, const float* __restrict__ hbuf,
    const float* __restrict__ bias, float* __restrict__ out, int N) {
    __shared__ float wkes[128];
    int t = threadIdx.x;
    if (t < 128) wkes[t] = wke[t];
    __syncthreads();
    int lane = t & 63;
    int sub = lane & 15;
    int grp = lane >> 4;
    int n = blockIdx.x * 4 + (t >> 6);
    if (n >= N) return;
    int cnt  = count[n];
    int base = offs[n];
    const float4 wa = *(const float4*)(wkes + sub * 4);
    const float4 wb = *(const float4*)(wkes + 64 + sub * 4);
    float ad0 = a_dst[n * 2 + 0], ad1 = a_dst[n * 2 + 1];
    float accx = 0.f, accy = 0.f, accz = 0.f, accw = 0.f;
    float den0 = 0.f, den1 = 0.f, sae0 = 0.f, sae1 = 0.f;

    if (cnt > 0) {
        int last = cnt - 1;
        int2 epA = epos[base + (grp < cnt ? grp : last)];
        int2 epB = epos[base + (grp + 4 < cnt ? grp + 4 : last)];
        float4 eaA = *(const float4*)(edge_attr + (size_t)epA.x * 64 + sub * 4);
        float2 asA = *(const float2*)(a_src + 2 * (size_t)epA.y);
        float4 hvA = *(const float4*)(hbuf + (size_t)epA.y * 64 + sub * 4);
        for (int j = grp; j < cnt; j += 4) {
            int jc = j + 8 < cnt ? j + 8 : last;
            int2 epC = epos[base + jc];
            float4 eaB = *(const float4*)(edge_attr + (size_t)epB.x * 64 + sub * 4);
            float2 asB = *(const float2*)(a_src + 2 * (size_t)epB.y);
            float4 hvB = *(const float4*)(hbuf + (size_t)epB.y * 64 + sub * 4);
            // ---- compute with stage-A state ----
            float pa0 = eaA.x * wa.x + eaA.y * wa.y + eaA.z * wa.z + eaA.w * wa.w;
            float pa1 = eaA.x * wb.x + eaA.y * wb.y + eaA.z * wb.z + eaA.w * wb.w;
#pragma unroll
            for (int m = 1; m <= 8; m <<= 1) {
                pa0 += __shfl_xor(pa0, m, 64);
                pa1 += __shfl_xor(pa1, m, 64);
            }
            float l0 = asA.x + ad0 + pa0; l0 = l0 > 0.f ? l0 : NEG * l0;
            float l1 = asA.y + ad1 + pa1; l1 = l1 > 0.f ? l1 : NEG * l1;
            float q0 = __expf(l0), q1 = __expf(l1);
            float q = (sub < 8) ? q0 : q1;
            accx = fmaf(q, hvA.x, accx);
            accy = fmaf(q, hvA.y, accy);
            accz = fmaf(q, hvA.z, accz);
            accw = fmaf(q, hvA.w, accw);
            den0 += q0; den1 += q1;
            sae0 += pa0; sae1 += pa1;
            // ---- shift pipeline ----
            epA = epB; eaA = eaB; asA = asB; hvA = hvB;
            epB = epC;
        }
    }
#define RED2(v) { v += __shfl_xor(v, 16, 64); v += __shfl_xor(v, 32, 64); }
    RED2(accx) RED2(accy) RED2(accz) RED2(accw)
    RED2(den0) RED2(den1) RED2(sae0) RED2(sae1)
#undef RED2

    float dg = (cnt > 0) ? (float)cnt : 1.f;
    float as0 = a_src[n * 2 + 0], as1 = a_src[n * 2 + 1];
    float l0 = as0 + ad0 + sae0 / dg; l0 = l0 > 0.f ? l0 : NEG * l0;
    float l1 = as1 + ad1 + sae1 / dg; l1 = l1 > 0.f ? l1 : NEG * l1;
    float pl0 = __expf(l0), pl1 = __expf(l1);
    const float4 hn = *(const float4*)(hbuf + (size_t)n * 64 + sub * 4);
    float pl  = (sub < 8) ? pl0 : pl1;
    float den = ((sub < 8) ? den0 + pl0 : den1 + pl1) + 1e-16f;
    const float4 bv = *(const float4*)(bias + sub * 4);
    if (grp == 0) {
        float4 o;
        o.x = (accx + pl * hn.x) / den + bv.x;
        o.y = (accy + pl * hn.y) / den + bv.y;
        o.z = (accz + pl * hn.z) / den + bv.z;
        o.w = (accw + pl * hn.w) / den + bv.w;
        *(float4*)(out + (size_t)n * 64 + sub * 4) = o;
    }
}

extern "C" void kernel_launch(void* const* d_in, const int* in_sizes, int n_in,
                              void* d_out, int out_size, void* d_ws, size_t ws_size,
                              hipStream_t stream) {
    const float* x         = (const float*)d_in[0];
    const int*   ei        = (const int*)d_in[1];
    const float* edge_attr = (const float*)d_in[2];
    const float* W         = (const float*)d_in[3];
    const float* W_edge    = (const float*)d_in[4];
    const float* att_src   = (const float*)d_in[5];
    const float* att_dst   = (const float*)d_in[6];
    const float* att_edge  = (const float*)d_in[7];
    const float* bias      = (const float*)d_in[8];

    int N = in_sizes[0] / 128;
    long long E = in_sizes[1] / 2;
    const int* srcI = ei;
    const int* dstI = ei + E;

    char* ws = (char*)d_ws;
    int2*  epos   = (int2*)ws;                        ws += (size_t)E * 8;
    float* wke    = (float*)ws;                       ws += 128 * 4;
    float* hbuf   = (float*)ws;                       ws += (size_t)N * 64 * 4;
    float* a_src  = (float*)ws;                       ws += (size_t)N * 2 * 4;
    float* a_dst  = (float*)ws;                       ws += (size_t)N * 2 * 4;
    int*   count  = (int*)ws;                         ws += (size_t)N * 4;
    int*   offs   = (int*)ws;                         ws += (size_t)N * 4;
    int*   cursor = (int*)ws;                         ws += (size_t)N * 4;
    int*   bsum   = (int*)ws;                         ws += 64 * 4;

    k_zero<<<(N + 255) / 256, 256, 0, stream>>>(count, N);
    k_node<<<(N + 31) / 32, 128, 0, stream>>>(x, W, att_src, att_dst, hbuf, a_src, a_dst, N);
    k_hist<<<2048, 256, 0, stream>>>(dstI, count, E, W_edge, att_edge, wke);

    int nb = (N + 1023) / 1024;
    k_scan1<<<nb, 256, 0, stream>>>(count, offs, bsum, N);
    k_scan2<<<1, 64, 0, stream>>>(bsum, nb);
    k_scan3<<<(N + 255) / 256, 256, 0, stream>>>(offs, bsum, cursor, N);

    k_sort<<<2048, 256, 0, stream>>>(srcI, dstI, cursor, epos, E);

    k_agg<<<(N + 3) / 4, 256, 0, stream>>>(epos, offs, count, edge_attr, wke, a_src, a_dst,
                                           hbuf, bias, (float*)d_out, N);
}